// Round 1
// baseline (205.868 us; speedup 1.0000x reference)
//
#include <hip/hip_runtime.h>
#include <hip/hip_bf16.h>

typedef __bf16 bf16x8 __attribute__((ext_vector_type(8)));
typedef __bf16 bf16x4 __attribute__((ext_vector_type(4)));
typedef float  f32x4  __attribute__((ext_vector_type(4)));

#define N_NODES 100000
#define N_EDGES 1000000
#define LATENT  64
#define HID     256
#define RBF_DIM 32
#define NTYPES  10
#define NCHG    6
#define NBOND   5

#define EDGE_TILES (N_EDGES / 32)   // 31250
#define NBLK 1024

// ---------------------------------------------------------------------------
// Atom MLP: h = relu(q @ aW1 + ab1); logits = h @ aW2 + ab2
// 32 nodes per block, 256 threads. Pure f32 VALU.
// ---------------------------------------------------------------------------
__global__ __launch_bounds__(256) void atom_kernel(
    const float* __restrict__ q,   const float* __restrict__ aW1,
    const float* __restrict__ ab1, const float* __restrict__ aW2,
    const float* __restrict__ ab2, float* __restrict__ outA,
    float* __restrict__ outB)
{
    __shared__ float qs[32 * 64];        // 8 KB
    __shared__ float hs[32][257];        // 32.9 KB (pad +1 breaks bank stride)

    const int t = threadIdx.x;
    const int node0 = blockIdx.x * 32;

    // cooperative load: 32 rows x 64 f32 contiguous = 2048 f32 = 512 float4
    const float4* qv = (const float4*)(q + (size_t)node0 * 64);
    float4* qsv = (float4*)qs;
    qsv[t]       = qv[t];
    qsv[t + 256] = qv[t + 256];
    __syncthreads();

    // layer 1: thread t owns output column t
    float acc[32];
    #pragma unroll
    for (int n = 0; n < 32; ++n) acc[n] = 0.f;

    for (int k0 = 0; k0 < 64; k0 += 8) {
        float w[8];
        #pragma unroll
        for (int j = 0; j < 8; ++j) w[j] = aW1[(k0 + j) * HID + t];
        #pragma unroll
        for (int n = 0; n < 32; ++n) {
            float4 qa = *(const float4*)(&qs[n * 64 + k0]);
            float4 qb = *(const float4*)(&qs[n * 64 + k0 + 4]);
            acc[n] = fmaf(qa.x, w[0], acc[n]);
            acc[n] = fmaf(qa.y, w[1], acc[n]);
            acc[n] = fmaf(qa.z, w[2], acc[n]);
            acc[n] = fmaf(qa.w, w[3], acc[n]);
            acc[n] = fmaf(qb.x, w[4], acc[n]);
            acc[n] = fmaf(qb.y, w[5], acc[n]);
            acc[n] = fmaf(qb.z, w[6], acc[n]);
            acc[n] = fmaf(qb.w, w[7], acc[n]);
        }
    }
    const float b1 = ab1[t];
    #pragma unroll
    for (int n = 0; n < 32; ++n) hs[n][t] = fmaxf(acc[n] + b1, 0.f);
    __syncthreads();

    // layer 2: thread -> (node n, output o) and (n+16, o); 256 K serial
    const int n = t >> 4;
    const int o = t & 15;
    float s0 = ab2[o], s1 = ab2[o];
    #pragma unroll 8
    for (int k = 0; k < 256; ++k) {
        const float w = aW2[k * 16 + o];
        s0 = fmaf(hs[n][k],      w, s0);
        s1 = fmaf(hs[n + 16][k], w, s1);
    }
    const int na = node0 + n, nb = node0 + n + 16;
    if (o < NTYPES) {
        outA[na * NTYPES + o] = s0;
        outA[nb * NTYPES + o] = s1;
    } else {
        outB[na * NCHG + (o - NTYPES)] = s0;
        outB[nb * NCHG + (o - NTYPES)] = s1;
    }
}

// ---------------------------------------------------------------------------
// Edge MLP, bf16 MFMA. 32 edges/tile, 4 waves, persistent grid-stride blocks.
// combined[32][96] staged bf16 in LDS (rows padded to 104).
// Layer 1: wave w owns cols [w*64, w*64+64); bW1 frags in registers.
// Layer 2: N padded 5->16, K=256 split 64/wave, LDS cross-wave reduce.
// ---------------------------------------------------------------------------
struct __align__(16) ESmem {
    __bf16 comb[32][104];        // 6656 B   (row = 208 B, 16B-multiple)
    __bf16 hs[32][264];          // 16896 B  (row = 528 B, 16B-multiple)
    float  red[4][2][4][64];     // 8192 B
};

__global__ __launch_bounds__(256, 2) void edge_kernel(
    const float* __restrict__ pos, const float* __restrict__ q,
    const int*   __restrict__ pair,
    const float* __restrict__ bW1, const float* __restrict__ bb1,
    const float* __restrict__ bW2, const float* __restrict__ bb2,
    float* __restrict__ outC)
{
    __shared__ ESmem sm;
    const int t    = threadIdx.x;
    const int w    = t >> 6;
    const int lane = t & 63;
    const int l15  = lane & 15;
    const int hi   = lane >> 4;
    const int wcol = w * 64;

    // ---- per-block constant fragments (live across the whole tile loop) ----
    bf16x8 bw1f[3][4];
    #pragma unroll
    for (int kb = 0; kb < 3; ++kb) {
        #pragma unroll
        for (int nt = 0; nt < 4; ++nt) {
            const int nn = wcol + nt * 16 + l15;
            const int k0 = kb * 32 + hi * 8;
            bf16x8 v;
            #pragma unroll
            for (int j = 0; j < 8; ++j) v[j] = (__bf16)bW1[(k0 + j) * HID + nn];
            bw1f[kb][nt] = v;
        }
    }
    bf16x8 bw2f[2];
    #pragma unroll
    for (int kk = 0; kk < 2; ++kk) {
        const int k0 = (w * 2 + kk) * 32 + hi * 8;
        bf16x8 v;
        #pragma unroll
        for (int j = 0; j < 8; ++j) {
            const float val = (l15 < NBOND) ? bW2[(k0 + j) * NBOND + l15] : 0.f;
            v[j] = (__bf16)val;
        }
        bw2f[kk] = v;
    }
    float b1reg[4];
    #pragma unroll
    for (int nt = 0; nt < 4; ++nt) b1reg[nt] = bb1[wcol + nt * 16 + l15];

    const int m_st = t >> 3;   // staging: edge slot 0..31
    const int p_st = t & 7;    // staging: 8 threads per edge

    for (int tile = blockIdx.x; tile < EDGE_TILES; tile += NBLK) {
        const int e0 = tile * 32;

        // ---------------- stage combined (bf16) ----------------
        {
            const int e   = e0 + m_st;
            const int src = pair[2 * e];
            const int dst = pair[2 * e + 1];
            const float* qa = q + (size_t)src * 64 + p_st * 8;
            const float* qb = q + (size_t)dst * 64 + p_st * 8;
            const float4 a0 = *(const float4*)(qa);
            const float4 a1 = *(const float4*)(qa + 4);
            const float4 c0 = *(const float4*)(qb);
            const float4 c1 = *(const float4*)(qb + 4);
            bf16x8 pf;
            pf[0] = (__bf16)(a0.x + c0.x);
            pf[1] = (__bf16)(a0.y + c0.y);
            pf[2] = (__bf16)(a0.z + c0.z);
            pf[3] = (__bf16)(a0.w + c0.w);
            pf[4] = (__bf16)(a1.x + c1.x);
            pf[5] = (__bf16)(a1.y + c1.y);
            pf[6] = (__bf16)(a1.z + c1.z);
            pf[7] = (__bf16)(a1.w + c1.w);
            *(bf16x8*)(&sm.comb[m_st][p_st * 8]) = pf;

            // rbf: 4 cols per thread
            const float dx = pos[src * 3 + 0] - pos[dst * 3 + 0];
            const float dy = pos[src * 3 + 1] - pos[dst * 3 + 1];
            const float dz = pos[src * 3 + 2] - pos[dst * 3 + 2];
            const float D  = sqrtf(fmaxf(dx * dx + dy * dy + dz * dz, 1e-8f));
            bf16x4 rv;
            #pragma unroll
            for (int j = 0; j < 4; ++j) {
                const int   c  = p_st * 4 + j;
                const float mu = (float)c * (10.0f / 31.0f);
                const float z  = (D - mu) * 3.2f;      // 1/sigma = 32/10
                rv[j] = (__bf16)__expf(-z * z);
            }
            *(bf16x4*)(&sm.comb[m_st][64 + p_st * 4]) = rv;
        }
        __syncthreads();

        // ---------------- layer 1 MFMA ----------------
        f32x4 acc[2][4];
        #pragma unroll
        for (int mt = 0; mt < 2; ++mt)
            #pragma unroll
            for (int nt = 0; nt < 4; ++nt) {
                f32x4 z = {0.f, 0.f, 0.f, 0.f};
                acc[mt][nt] = z;
            }
        #pragma unroll
        for (int kb = 0; kb < 3; ++kb) {
            #pragma unroll
            for (int mt = 0; mt < 2; ++mt) {
                const bf16x8 af = *(const bf16x8*)((const char*)&sm.comb[0][0]
                                   + (mt * 16 + l15) * 208 + kb * 64 + hi * 16);
                #pragma unroll
                for (int nt = 0; nt < 4; ++nt)
                    acc[mt][nt] = __builtin_amdgcn_mfma_f32_16x16x32_bf16(
                        af, bw1f[kb][nt], acc[mt][nt], 0, 0, 0);
            }
        }
        // relu + bias -> hs (bf16)
        #pragma unroll
        for (int mt = 0; mt < 2; ++mt)
            #pragma unroll
            for (int nt = 0; nt < 4; ++nt)
                #pragma unroll
                for (int r = 0; r < 4; ++r) {
                    const float v = fmaxf(acc[mt][nt][r] + b1reg[nt], 0.f);
                    sm.hs[mt * 16 + hi * 4 + r][wcol + nt * 16 + l15] = (__bf16)v;
                }
        __syncthreads();

        // ---------------- layer 2 MFMA (K split across waves) ----------------
        f32x4 acc2[2];
        {
            f32x4 z = {0.f, 0.f, 0.f, 0.f};
            acc2[0] = z; acc2[1] = z;
        }
        #pragma unroll
        for (int mt = 0; mt < 2; ++mt)
            #pragma unroll
            for (int kk = 0; kk < 2; ++kk) {
                const int kb = w * 2 + kk;
                const bf16x8 af = *(const bf16x8*)((const char*)&sm.hs[0][0]
                                   + (mt * 16 + l15) * 528 + kb * 64 + hi * 16);
                acc2[mt] = __builtin_amdgcn_mfma_f32_16x16x32_bf16(
                    af, bw2f[kk], acc2[mt], 0, 0, 0);
            }
        #pragma unroll
        for (int mt = 0; mt < 2; ++mt)
            #pragma unroll
            for (int r = 0; r < 4; ++r)
                sm.red[w][mt][r][lane] = acc2[mt][r];
        __syncthreads();

        // ---------------- epilogue: reduce 4 waves, write bond logits ----------------
        if (t < 160) {
            const int m = t / 5, o = t % 5;
            const int mt = m >> 4, row16 = m & 15;
            const int hh = row16 >> 2, r = row16 & 3;
            float s = bb2[o];
            #pragma unroll
            for (int ww = 0; ww < 4; ++ww) s += sm.red[ww][mt][r][hh * 16 + o];
            outC[(size_t)(e0 + m) * NBOND + o] = s;
        }
        __syncthreads();
    }
}

// ---------------------------------------------------------------------------
extern "C" void kernel_launch(void* const* d_in, const int* in_sizes, int n_in,
                              void* d_out, int out_size, void* d_ws, size_t ws_size,
                              hipStream_t stream)
{
    const float* pos = (const float*)d_in[0];
    const float* q   = (const float*)d_in[1];
    const int*   pair= (const int*)  d_in[2];
    const float* aW1 = (const float*)d_in[3];
    const float* ab1 = (const float*)d_in[4];
    const float* aW2 = (const float*)d_in[5];
    const float* ab2 = (const float*)d_in[6];
    const float* bW1 = (const float*)d_in[7];
    const float* bb1 = (const float*)d_in[8];
    const float* bW2 = (const float*)d_in[9];
    const float* bb2 = (const float*)d_in[10];

    float* out  = (float*)d_out;
    float* outA = out;                                  // 100000 x 10
    float* outB = out + (size_t)N_NODES * NTYPES;       // 100000 x 6
    float* outC = out + (size_t)N_NODES * (NTYPES + NCHG); // 1000000 x 5

    hipLaunchKernelGGL(atom_kernel, dim3(N_NODES / 32), dim3(256), 0, stream,
                       q, aW1, ab1, aW2, ab2, outA, outB);
    hipLaunchKernelGGL(edge_kernel, dim3(NBLK), dim3(256), 0, stream,
                       pos, q, pair, bW1, bb1, bW2, bb2, outC);
}

// Round 2
// 144.390 us; speedup vs baseline: 1.4258x; 1.4258x over previous
//
#include <hip/hip_runtime.h>
#include <hip/hip_bf16.h>

typedef __bf16 bf16x8 __attribute__((ext_vector_type(8)));
typedef __bf16 bf16x4 __attribute__((ext_vector_type(4)));
typedef float  f32x4  __attribute__((ext_vector_type(4)));

#define N_NODES 100000
#define N_EDGES 1000000
#define LATENT  64
#define HID     256
#define RBF_DIM 32
#define NTYPES  10
#define NCHG    6
#define NBOND   5

#define EDGE_TILES (N_EDGES / 32)   // 31250
#define NBLK 1024

#define ATOM_TILES (N_NODES / 32)   // 3125
#define ANBLK 512

// ---------------------------------------------------------------------------
// Atom MLP via MFMA: h = relu(q @ aW1 + ab1); logits = h @ aW2 + ab2
// 32 nodes/tile, 4 waves, persistent blocks. Layer-1 computed as
// h^T = aW1^T @ q^T (operand-swapped) so relu-store is 4-contiguous (b64).
// Layer-2: N=16 exact, K=256 split 64/wave, LDS cross-wave reduce.
// ---------------------------------------------------------------------------
struct __align__(16) ASmem {
    __bf16 qs[32][72];           // 4608 B  (row = 144 B)
    __bf16 hsE[32][264];         // 16896 B (row = 528 B) [edge-major: node][hidden]
    float  red[4][2][4][64];     // 8192 B
};

__global__ __launch_bounds__(256, 2) void atom_kernel(
    const float* __restrict__ q,   const float* __restrict__ aW1,
    const float* __restrict__ ab1, const float* __restrict__ aW2,
    const float* __restrict__ ab2, float* __restrict__ outA,
    float* __restrict__ outB)
{
    __shared__ ASmem sm;
    const int t    = threadIdx.x;
    const int w    = t >> 6;
    const int lane = t & 63;
    const int l15  = lane & 15;
    const int hi   = lane >> 4;
    const int wcol = w * 64;

    // per-block constant fragments
    bf16x8 aw1f[2][4];                 // A' = aW1^T  [kb][nt]
    #pragma unroll
    for (int kb = 0; kb < 2; ++kb)
        #pragma unroll
        for (int nt = 0; nt < 4; ++nt) {
            const int nn = wcol + nt * 16 + l15;
            const int k0 = kb * 32 + hi * 8;
            bf16x8 v;
            #pragma unroll
            for (int j = 0; j < 8; ++j) v[j] = (__bf16)aW1[(k0 + j) * HID + nn];
            aw1f[kb][nt] = v;
        }
    bf16x8 aw2f[2];                    // B for layer 2 (N=16 exact)
    #pragma unroll
    for (int kk = 0; kk < 2; ++kk) {
        const int k0 = (w * 2 + kk) * 32 + hi * 8;
        bf16x8 v;
        #pragma unroll
        for (int j = 0; j < 8; ++j) v[j] = (__bf16)aW2[(k0 + j) * 16 + l15];
        aw2f[kk] = v;
    }
    float4 b1v[4];                     // bias indexed by hidden = wcol+nt*16+hi*4+r
    #pragma unroll
    for (int nt = 0; nt < 4; ++nt)
        b1v[nt] = *(const float4*)(&ab1[wcol + nt * 16 + hi * 4]);

    const int m_st = t >> 3;           // staging row 0..31
    const int p_st = t & 7;

    for (int tile = blockIdx.x; tile < ATOM_TILES; tile += ANBLK) {
        const int node0 = tile * 32;

        // stage q tile -> bf16 LDS
        {
            const float* qr = q + (size_t)(node0 + m_st) * 64 + p_st * 8;
            const float4 a0 = *(const float4*)(qr);
            const float4 a1 = *(const float4*)(qr + 4);
            bf16x8 v;
            v[0] = (__bf16)a0.x; v[1] = (__bf16)a0.y; v[2] = (__bf16)a0.z; v[3] = (__bf16)a0.w;
            v[4] = (__bf16)a1.x; v[5] = (__bf16)a1.y; v[6] = (__bf16)a1.z; v[7] = (__bf16)a1.w;
            *(bf16x8*)(&sm.qs[m_st][p_st * 8]) = v;
        }
        __syncthreads();

        // layer 1 (swapped): D[hidden][node]
        f32x4 acc[2][4];
        #pragma unroll
        for (int mt = 0; mt < 2; ++mt)
            #pragma unroll
            for (int nt = 0; nt < 4; ++nt) {
                f32x4 z = {0.f, 0.f, 0.f, 0.f};
                acc[mt][nt] = z;
            }
        #pragma unroll
        for (int kb = 0; kb < 2; ++kb)
            #pragma unroll
            for (int mt = 0; mt < 2; ++mt) {
                const bf16x8 bq = *(const bf16x8*)((const char*)&sm.qs[0][0]
                                   + (mt * 16 + l15) * 144 + kb * 64 + hi * 16);
                #pragma unroll
                for (int nt = 0; nt < 4; ++nt)
                    acc[mt][nt] = __builtin_amdgcn_mfma_f32_16x16x32_bf16(
                        aw1f[kb][nt], bq, acc[mt][nt], 0, 0, 0);
            }
        // relu + bias -> hsE[node][hidden], 4-contiguous in hidden -> b64
        #pragma unroll
        for (int mt = 0; mt < 2; ++mt)
            #pragma unroll
            for (int nt = 0; nt < 4; ++nt) {
                bf16x4 hv;
                #pragma unroll
                for (int r = 0; r < 4; ++r)
                    hv[r] = (__bf16)fmaxf(acc[mt][nt][r] + ((const float*)&b1v[nt])[r], 0.f);
                *(bf16x4*)(&sm.hsE[mt * 16 + l15][wcol + nt * 16 + hi * 4]) = hv;
            }
        __syncthreads();

        // layer 2: D[node][o], K split across waves
        f32x4 acc2[2];
        {
            f32x4 z = {0.f, 0.f, 0.f, 0.f};
            acc2[0] = z; acc2[1] = z;
        }
        #pragma unroll
        for (int mt = 0; mt < 2; ++mt)
            #pragma unroll
            for (int kk = 0; kk < 2; ++kk) {
                const int kb = w * 2 + kk;
                const bf16x8 af = *(const bf16x8*)((const char*)&sm.hsE[0][0]
                                   + (mt * 16 + l15) * 528 + kb * 64 + hi * 16);
                acc2[mt] = __builtin_amdgcn_mfma_f32_16x16x32_bf16(
                    af, aw2f[kk], acc2[mt], 0, 0, 0);
            }
        #pragma unroll
        for (int mt = 0; mt < 2; ++mt)
            #pragma unroll
            for (int r = 0; r < 4; ++r)
                sm.red[w][mt][r][lane] = acc2[mt][r];
        __syncthreads();

        // epilogue: 512 outputs, 2 per thread
        {
            const int o  = t & 15;
            const int m0 = t >> 4;          // 0..15
            #pragma unroll
            for (int half = 0; half < 2; ++half) {
                const int m  = m0 + half * 16;
                const int mt = m >> 4, rr = m & 15;
                const int hh = rr >> 2, r = rr & 3;
                float s = ab2[o];
                #pragma unroll
                for (int ww = 0; ww < 4; ++ww) s += sm.red[ww][mt][r][hh * 16 + o];
                const int node = node0 + m;
                if (o < NTYPES) outA[node * NTYPES + o] = s;
                else            outB[node * NCHG + (o - NTYPES)] = s;
            }
        }
        __syncthreads();
    }
}

// ---------------------------------------------------------------------------
// Edge MLP, bf16 MFMA. 32 edges/tile, 4 waves, persistent grid-stride blocks.
// Layer-1 operand-swapped (h^T) so relu-store is b64-vectorized.
// ---------------------------------------------------------------------------
struct __align__(16) ESmem {
    __bf16 comb[32][104];        // 6656 B   (row = 208 B)
    __bf16 hsE[32][264];         // 16896 B  [edge][hidden]
    float  red[4][2][4][64];     // 8192 B
};

__global__ __launch_bounds__(256, 2) void edge_kernel(
    const float* __restrict__ pos, const float* __restrict__ q,
    const int*   __restrict__ pair,
    const float* __restrict__ bW1, const float* __restrict__ bb1,
    const float* __restrict__ bW2, const float* __restrict__ bb2,
    float* __restrict__ outC)
{
    __shared__ ESmem sm;
    const int t    = threadIdx.x;
    const int w    = t >> 6;
    const int lane = t & 63;
    const int l15  = lane & 15;
    const int hi   = lane >> 4;
    const int wcol = w * 64;

    // per-block constant fragments
    bf16x8 bw1f[3][4];                 // A' = bW1^T
    #pragma unroll
    for (int kb = 0; kb < 3; ++kb)
        #pragma unroll
        for (int nt = 0; nt < 4; ++nt) {
            const int nn = wcol + nt * 16 + l15;
            const int k0 = kb * 32 + hi * 8;
            bf16x8 v;
            #pragma unroll
            for (int j = 0; j < 8; ++j) v[j] = (__bf16)bW1[(k0 + j) * HID + nn];
            bw1f[kb][nt] = v;
        }
    bf16x8 bw2f[2];
    #pragma unroll
    for (int kk = 0; kk < 2; ++kk) {
        const int k0 = (w * 2 + kk) * 32 + hi * 8;
        bf16x8 v;
        #pragma unroll
        for (int j = 0; j < 8; ++j) {
            const float val = (l15 < NBOND) ? bW2[(k0 + j) * NBOND + l15] : 0.f;
            v[j] = (__bf16)val;
        }
        bw2f[kk] = v;
    }
    float4 b1v[4];                     // bias indexed by hidden = wcol+nt*16+hi*4+r
    #pragma unroll
    for (int nt = 0; nt < 4; ++nt)
        b1v[nt] = *(const float4*)(&bb1[wcol + nt * 16 + hi * 4]);

    const int m_st = t >> 3;
    const int p_st = t & 7;

    for (int tile = blockIdx.x; tile < EDGE_TILES; tile += NBLK) {
        const int e0 = tile * 32;

        // ---------------- stage combined (bf16) ----------------
        {
            const int e   = e0 + m_st;
            const int src = pair[2 * e];
            const int dst = pair[2 * e + 1];
            const float* qa = q + (size_t)src * 64 + p_st * 8;
            const float* qb = q + (size_t)dst * 64 + p_st * 8;
            const float4 a0 = *(const float4*)(qa);
            const float4 a1 = *(const float4*)(qa + 4);
            const float4 c0 = *(const float4*)(qb);
            const float4 c1 = *(const float4*)(qb + 4);
            bf16x8 pf;
            pf[0] = (__bf16)(a0.x + c0.x);
            pf[1] = (__bf16)(a0.y + c0.y);
            pf[2] = (__bf16)(a0.z + c0.z);
            pf[3] = (__bf16)(a0.w + c0.w);
            pf[4] = (__bf16)(a1.x + c1.x);
            pf[5] = (__bf16)(a1.y + c1.y);
            pf[6] = (__bf16)(a1.z + c1.z);
            pf[7] = (__bf16)(a1.w + c1.w);
            *(bf16x8*)(&sm.comb[m_st][p_st * 8]) = pf;

            const float dx = pos[src * 3 + 0] - pos[dst * 3 + 0];
            const float dy = pos[src * 3 + 1] - pos[dst * 3 + 1];
            const float dz = pos[src * 3 + 2] - pos[dst * 3 + 2];
            const float D  = sqrtf(fmaxf(dx * dx + dy * dy + dz * dz, 1e-8f));
            bf16x4 rv;
            #pragma unroll
            for (int j = 0; j < 4; ++j) {
                const int   c  = p_st * 4 + j;
                const float mu = (float)c * (10.0f / 31.0f);
                const float z  = (D - mu) * 3.2f;
                rv[j] = (__bf16)__expf(-z * z);
            }
            *(bf16x4*)(&sm.comb[m_st][64 + p_st * 4]) = rv;
        }
        __syncthreads();

        // ---------------- layer 1 MFMA (swapped): D[hidden][edge] ----------------
        f32x4 acc[2][4];
        #pragma unroll
        for (int mt = 0; mt < 2; ++mt)
            #pragma unroll
            for (int nt = 0; nt < 4; ++nt) {
                f32x4 z = {0.f, 0.f, 0.f, 0.f};
                acc[mt][nt] = z;
            }
        #pragma unroll
        for (int kb = 0; kb < 3; ++kb)
            #pragma unroll
            for (int mt = 0; mt < 2; ++mt) {
                const bf16x8 af = *(const bf16x8*)((const char*)&sm.comb[0][0]
                                   + (mt * 16 + l15) * 208 + kb * 64 + hi * 16);
                #pragma unroll
                for (int nt = 0; nt < 4; ++nt)
                    acc[mt][nt] = __builtin_amdgcn_mfma_f32_16x16x32_bf16(
                        bw1f[kb][nt], af, acc[mt][nt], 0, 0, 0);
            }
        // relu + bias -> hsE[edge][hidden], b64 stores
        #pragma unroll
        for (int mt = 0; mt < 2; ++mt)
            #pragma unroll
            for (int nt = 0; nt < 4; ++nt) {
                bf16x4 hv;
                #pragma unroll
                for (int r = 0; r < 4; ++r)
                    hv[r] = (__bf16)fmaxf(acc[mt][nt][r] + ((const float*)&b1v[nt])[r], 0.f);
                *(bf16x4*)(&sm.hsE[mt * 16 + l15][wcol + nt * 16 + hi * 4]) = hv;
            }
        __syncthreads();

        // ---------------- layer 2 MFMA (K split across waves) ----------------
        f32x4 acc2[2];
        {
            f32x4 z = {0.f, 0.f, 0.f, 0.f};
            acc2[0] = z; acc2[1] = z;
        }
        #pragma unroll
        for (int mt = 0; mt < 2; ++mt)
            #pragma unroll
            for (int kk = 0; kk < 2; ++kk) {
                const int kb = w * 2 + kk;
                const bf16x8 af = *(const bf16x8*)((const char*)&sm.hsE[0][0]
                                   + (mt * 16 + l15) * 528 + kb * 64 + hi * 16);
                acc2[mt] = __builtin_amdgcn_mfma_f32_16x16x32_bf16(
                    af, bw2f[kk], acc2[mt], 0, 0, 0);
            }
        #pragma unroll
        for (int mt = 0; mt < 2; ++mt)
            #pragma unroll
            for (int r = 0; r < 4; ++r)
                sm.red[w][mt][r][lane] = acc2[mt][r];
        __syncthreads();

        // ---------------- epilogue ----------------
        if (t < 160) {
            const int m = t / 5, o = t % 5;
            const int mt = m >> 4, row16 = m & 15;
            const int hh = row16 >> 2, r = row16 & 3;
            float s = bb2[o];
            #pragma unroll
            for (int ww = 0; ww < 4; ++ww) s += sm.red[ww][mt][r][hh * 16 + o];
            outC[(size_t)(e0 + m) * NBOND + o] = s;
        }
        __syncthreads();
    }
}

// ---------------------------------------------------------------------------
extern "C" void kernel_launch(void* const* d_in, const int* in_sizes, int n_in,
                              void* d_out, int out_size, void* d_ws, size_t ws_size,
                              hipStream_t stream)
{
    const float* pos = (const float*)d_in[0];
    const float* q   = (const float*)d_in[1];
    const int*   pair= (const int*)  d_in[2];
    const float* aW1 = (const float*)d_in[3];
    const float* ab1 = (const float*)d_in[4];
    const float* aW2 = (const float*)d_in[5];
    const float* ab2 = (const float*)d_in[6];
    const float* bW1 = (const float*)d_in[7];
    const float* bb1 = (const float*)d_in[8];
    const float* bW2 = (const float*)d_in[9];
    const float* bb2 = (const float*)d_in[10];

    float* out  = (float*)d_out;
    float* outA = out;
    float* outB = out + (size_t)N_NODES * NTYPES;
    float* outC = out + (size_t)N_NODES * (NTYPES + NCHG);

    hipLaunchKernelGGL(atom_kernel, dim3(ANBLK), dim3(256), 0, stream,
                       q, aW1, ab1, aW2, ab2, outA, outB);
    hipLaunchKernelGGL(edge_kernel, dim3(NBLK), dim3(256), 0, stream,
                       pos, q, pair, bW1, bb1, bW2, bb2, outC);
}

// Round 3
// 101.885 us; speedup vs baseline: 2.0206x; 1.4172x over previous
//
#include <hip/hip_runtime.h>
#include <hip/hip_bf16.h>

typedef __bf16 bf16x8 __attribute__((ext_vector_type(8)));
typedef __bf16 bf16x4 __attribute__((ext_vector_type(4)));
typedef float  f32x4  __attribute__((ext_vector_type(4)));

#define N_NODES 100000
#define N_EDGES 1000000
#define LATENT  64
#define HID     256
#define RBF_DIM 32
#define NTYPES  10
#define NCHG    6
#define NBOND   5

#define ATOM_TILES (N_NODES / 32)   // 3125
#define ANBLK 512

#define ETILE  64
#define ETILES (N_EDGES / ETILE)    // 15625
#define ENBLK  512

// ---------------------------------------------------------------------------
// prep: q (f32) -> qb (bf16), 8 elems/thread, exact grid 3125x256
// ---------------------------------------------------------------------------
__global__ __launch_bounds__(256) void prep_kernel(
    const float* __restrict__ q, __bf16* __restrict__ qb)
{
    const int i = blockIdx.x * 256 + threadIdx.x;   // octet index, < 800000
    const float4 a = *(const float4*)(q + (size_t)i * 8);
    const float4 b = *(const float4*)(q + (size_t)i * 8 + 4);
    bf16x8 v;
    v[0] = (__bf16)a.x; v[1] = (__bf16)a.y; v[2] = (__bf16)a.z; v[3] = (__bf16)a.w;
    v[4] = (__bf16)b.x; v[5] = (__bf16)b.y; v[6] = (__bf16)b.z; v[7] = (__bf16)b.w;
    *(bf16x8*)(qb + (size_t)i * 8) = v;
}

// ---------------------------------------------------------------------------
// Atom MLP via MFMA (unchanged from round 2; ~2.5 us)
// ---------------------------------------------------------------------------
struct __align__(16) ASmem {
    __bf16 qs[32][72];
    __bf16 hsE[32][264];
    float  red[4][2][4][64];
};

__global__ __launch_bounds__(256, 2) void atom_kernel(
    const float* __restrict__ q,   const float* __restrict__ aW1,
    const float* __restrict__ ab1, const float* __restrict__ aW2,
    const float* __restrict__ ab2, float* __restrict__ outA,
    float* __restrict__ outB)
{
    __shared__ ASmem sm;
    const int t    = threadIdx.x;
    const int w    = t >> 6;
    const int lane = t & 63;
    const int l15  = lane & 15;
    const int hi   = lane >> 4;
    const int wcol = w * 64;

    bf16x8 aw1f[2][4];
    #pragma unroll
    for (int kb = 0; kb < 2; ++kb)
        #pragma unroll
        for (int nt = 0; nt < 4; ++nt) {
            const int nn = wcol + nt * 16 + l15;
            const int k0 = kb * 32 + hi * 8;
            bf16x8 v;
            #pragma unroll
            for (int j = 0; j < 8; ++j) v[j] = (__bf16)aW1[(k0 + j) * HID + nn];
            aw1f[kb][nt] = v;
        }
    bf16x8 aw2f[2];
    #pragma unroll
    for (int kk = 0; kk < 2; ++kk) {
        const int k0 = (w * 2 + kk) * 32 + hi * 8;
        bf16x8 v;
        #pragma unroll
        for (int j = 0; j < 8; ++j) v[j] = (__bf16)aW2[(k0 + j) * 16 + l15];
        aw2f[kk] = v;
    }
    float4 b1v[4];
    #pragma unroll
    for (int nt = 0; nt < 4; ++nt)
        b1v[nt] = *(const float4*)(&ab1[wcol + nt * 16 + hi * 4]);

    const int m_st = t >> 3;
    const int p_st = t & 7;

    for (int tile = blockIdx.x; tile < ATOM_TILES; tile += ANBLK) {
        const int node0 = tile * 32;
        {
            const float* qr = q + (size_t)(node0 + m_st) * 64 + p_st * 8;
            const float4 a0 = *(const float4*)(qr);
            const float4 a1 = *(const float4*)(qr + 4);
            bf16x8 v;
            v[0] = (__bf16)a0.x; v[1] = (__bf16)a0.y; v[2] = (__bf16)a0.z; v[3] = (__bf16)a0.w;
            v[4] = (__bf16)a1.x; v[5] = (__bf16)a1.y; v[6] = (__bf16)a1.z; v[7] = (__bf16)a1.w;
            *(bf16x8*)(&sm.qs[m_st][p_st * 8]) = v;
        }
        __syncthreads();

        f32x4 acc[2][4];
        #pragma unroll
        for (int mt = 0; mt < 2; ++mt)
            #pragma unroll
            for (int nt = 0; nt < 4; ++nt) {
                f32x4 z = {0.f, 0.f, 0.f, 0.f};
                acc[mt][nt] = z;
            }
        #pragma unroll
        for (int kb = 0; kb < 2; ++kb)
            #pragma unroll
            for (int mt = 0; mt < 2; ++mt) {
                const bf16x8 bq = *(const bf16x8*)((const char*)&sm.qs[0][0]
                                   + (mt * 16 + l15) * 144 + kb * 64 + hi * 16);
                #pragma unroll
                for (int nt = 0; nt < 4; ++nt)
                    acc[mt][nt] = __builtin_amdgcn_mfma_f32_16x16x32_bf16(
                        aw1f[kb][nt], bq, acc[mt][nt], 0, 0, 0);
            }
        #pragma unroll
        for (int mt = 0; mt < 2; ++mt)
            #pragma unroll
            for (int nt = 0; nt < 4; ++nt) {
                bf16x4 hv;
                #pragma unroll
                for (int r = 0; r < 4; ++r)
                    hv[r] = (__bf16)fmaxf(acc[mt][nt][r] + ((const float*)&b1v[nt])[r], 0.f);
                *(bf16x4*)(&sm.hsE[mt * 16 + l15][wcol + nt * 16 + hi * 4]) = hv;
            }
        __syncthreads();

        f32x4 acc2[2];
        {
            f32x4 z = {0.f, 0.f, 0.f, 0.f};
            acc2[0] = z; acc2[1] = z;
        }
        #pragma unroll
        for (int mt = 0; mt < 2; ++mt)
            #pragma unroll
            for (int kk = 0; kk < 2; ++kk) {
                const int kb = w * 2 + kk;
                const bf16x8 af = *(const bf16x8*)((const char*)&sm.hsE[0][0]
                                   + (mt * 16 + l15) * 528 + kb * 64 + hi * 16);
                acc2[mt] = __builtin_amdgcn_mfma_f32_16x16x32_bf16(
                    af, aw2f[kk], acc2[mt], 0, 0, 0);
            }
        #pragma unroll
        for (int mt = 0; mt < 2; ++mt)
            #pragma unroll
            for (int r = 0; r < 4; ++r)
                sm.red[w][mt][r][lane] = acc2[mt][r];
        __syncthreads();

        {
            const int o  = t & 15;
            const int m0 = t >> 4;
            #pragma unroll
            for (int half = 0; half < 2; ++half) {
                const int m  = m0 + half * 16;
                const int mt = m >> 4, rr = m & 15;
                const int hh = rr >> 2, r = rr & 3;
                float s = ab2[o];
                #pragma unroll
                for (int ww = 0; ww < 4; ++ww) s += sm.red[ww][mt][r][hh * 16 + o];
                const int node = node0 + m;
                if (o < NTYPES) outA[node * NTYPES + o] = s;
                else            outB[node * NCHG + (o - NTYPES)] = s;
            }
        }
        __syncthreads();
    }
}

// ---------------------------------------------------------------------------
// Edge MLP v3: 64-edge tiles, 512 threads (8 waves), 2 barriers/tile,
// deep prefetch (pair 2 tiles ahead, q/pos gather 1 tile ahead).
// Layer-1: N-split 32 cols/wave (W1 frags in regs). Layer-2: M-split on
// waves 0-3, W2 staged in LDS, direct global store (no reduction).
// ---------------------------------------------------------------------------
struct __align__(16) ESmem {
    __bf16 comb[ETILE][104];   // 13312 B
    __bf16 hsE[ETILE][264];    // 33792 B
    __bf16 w2t[16][264];       // 8448 B
};                             // 55552 B total

template<bool USEBF>
__global__ __launch_bounds__(512, 4) void edge_kernel(
    const float* __restrict__ pos, const float* __restrict__ qf,
    const __bf16* __restrict__ qb, const int* __restrict__ pair,
    const float* __restrict__ bW1, const float* __restrict__ bb1,
    const float* __restrict__ bW2, const float* __restrict__ bb2,
    float* __restrict__ outC)
{
    __shared__ ESmem sm;
    const int t    = threadIdx.x;
    const int w    = t >> 6;
    const int lane = t & 63;
    const int l15  = lane & 15;
    const int hi   = lane >> 4;
    const int wcol = w * 32;

    // one-time: W2 (padded to 16 cols) transposed into LDS [o][k]
    {
        const int o  = t >> 5;          // 0..15
        const int k0 = (t & 31) * 8;    // 0..248
        bf16x8 v;
        #pragma unroll
        for (int j = 0; j < 8; ++j)
            v[j] = (o < NBOND) ? (__bf16)bW2[(k0 + j) * NBOND + o] : (__bf16)0.f;
        *(bf16x8*)(&sm.w2t[o][k0]) = v;
    }

    // per-block constants
    bf16x8 bw1f[3][2];
    #pragma unroll
    for (int kb = 0; kb < 3; ++kb)
        #pragma unroll
        for (int nt = 0; nt < 2; ++nt) {
            const int nn = wcol + nt * 16 + l15;
            const int k0 = kb * 32 + hi * 8;
            bf16x8 v;
            #pragma unroll
            for (int j = 0; j < 8; ++j) v[j] = (__bf16)bW1[(k0 + j) * HID + nn];
            bw1f[kb][nt] = v;
        }
    float4 b1v[2];
    b1v[0] = *(const float4*)(&bb1[wcol + hi * 4]);
    b1v[1] = *(const float4*)(&bb1[wcol + 16 + hi * 4]);
    const float bb2v = (l15 < NBOND) ? bb2[l15] : 0.f;

    const int e_loc = t >> 3;   // 0..63: edge slot
    const int p     = t & 7;    // 8 threads/edge, 8 cols each

    // ---- prefetch state ----
    int tile = blockIdx.x;
    int2 pA = ((const int2*)pair)[(size_t)tile * ETILE + e_loc];   // cur tile
    bf16x8 gs, gd;
    float4 fs0, fs1, fd0, fd1;
    float  ps0, ps1, ps2, pd0, pd1, pd2;
    if constexpr (USEBF) {
        gs = *(const bf16x8*)(qb + (size_t)pA.x * 64 + p * 8);
        gd = *(const bf16x8*)(qb + (size_t)pA.y * 64 + p * 8);
    } else {
        fs0 = *(const float4*)(qf + (size_t)pA.x * 64 + p * 8);
        fs1 = *(const float4*)(qf + (size_t)pA.x * 64 + p * 8 + 4);
        fd0 = *(const float4*)(qf + (size_t)pA.y * 64 + p * 8);
        fd1 = *(const float4*)(qf + (size_t)pA.y * 64 + p * 8 + 4);
    }
    ps0 = pos[(size_t)pA.x * 3];  ps1 = pos[(size_t)pA.x * 3 + 1];  ps2 = pos[(size_t)pA.x * 3 + 2];
    pd0 = pos[(size_t)pA.y * 3];  pd1 = pos[(size_t)pA.y * 3 + 1];  pd2 = pos[(size_t)pA.y * 3 + 2];
    // pair for next tile
    {
        const int tn = tile + ENBLK;
        pA = ((const int2*)pair)[(tn < ETILES ? (size_t)tn * ETILE : 0) + e_loc];
    }
    __syncthreads();   // w2t visible (also first-iteration cleanliness)

    for (; tile < ETILES; tile += ENBLK) {
        const int e0 = tile * ETILE;

        // ---- stage comb(tile) from prefetched regs ----
        {
            bf16x8 cv;
            if constexpr (USEBF) {
                #pragma unroll
                for (int j = 0; j < 8; ++j)
                    cv[j] = (__bf16)((float)gs[j] + (float)gd[j]);
            } else {
                cv[0] = (__bf16)(fs0.x + fd0.x); cv[1] = (__bf16)(fs0.y + fd0.y);
                cv[2] = (__bf16)(fs0.z + fd0.z); cv[3] = (__bf16)(fs0.w + fd0.w);
                cv[4] = (__bf16)(fs1.x + fd1.x); cv[5] = (__bf16)(fs1.y + fd1.y);
                cv[6] = (__bf16)(fs1.z + fd1.z); cv[7] = (__bf16)(fs1.w + fd1.w);
            }
            *(bf16x8*)(&sm.comb[e_loc][p * 8]) = cv;

            const float dx = ps0 - pd0, dy = ps1 - pd1, dz = ps2 - pd2;
            const float D  = sqrtf(fmaxf(dx * dx + dy * dy + dz * dz, 1e-8f));
            bf16x4 rv;
            #pragma unroll
            for (int j = 0; j < 4; ++j) {
                const float mu = (float)(p * 4 + j) * (10.0f / 31.0f);
                const float z  = (D - mu) * 3.2f;
                rv[j] = (__bf16)__expf(-z * z);
            }
            *(bf16x4*)(&sm.comb[e_loc][64 + p * 4]) = rv;
        }
        __syncthreads();   // bar1: comb ready; hsE(t-1) reads all done

        // ---- issue prefetch for tile+ENBLK (latency hides under L1) ----
        {
            const int2 pN = pA;
            if constexpr (USEBF) {
                gs = *(const bf16x8*)(qb + (size_t)pN.x * 64 + p * 8);
                gd = *(const bf16x8*)(qb + (size_t)pN.y * 64 + p * 8);
            } else {
                fs0 = *(const float4*)(qf + (size_t)pN.x * 64 + p * 8);
                fs1 = *(const float4*)(qf + (size_t)pN.x * 64 + p * 8 + 4);
                fd0 = *(const float4*)(qf + (size_t)pN.y * 64 + p * 8);
                fd1 = *(const float4*)(qf + (size_t)pN.y * 64 + p * 8 + 4);
            }
            ps0 = pos[(size_t)pN.x * 3];  ps1 = pos[(size_t)pN.x * 3 + 1];  ps2 = pos[(size_t)pN.x * 3 + 2];
            pd0 = pos[(size_t)pN.y * 3];  pd1 = pos[(size_t)pN.y * 3 + 1];  pd2 = pos[(size_t)pN.y * 3 + 2];
            const int tnn = tile + 2 * ENBLK;
            pA = ((const int2*)pair)[(tnn < ETILES ? (size_t)tnn * ETILE : 0) + e_loc];
        }

        // ---- layer 1: D[hidden][edge], wave owns 32 hidden cols ----
        f32x4 acc[4][2];
        #pragma unroll
        for (int mt = 0; mt < 4; ++mt)
            #pragma unroll
            for (int nt = 0; nt < 2; ++nt) {
                f32x4 z = {0.f, 0.f, 0.f, 0.f};
                acc[mt][nt] = z;
            }
        #pragma unroll
        for (int kb = 0; kb < 3; ++kb)
            #pragma unroll
            for (int mt = 0; mt < 4; ++mt) {
                const bf16x8 bf = *(const bf16x8*)((const char*)&sm.comb[0][0]
                                   + (mt * 16 + l15) * 208 + kb * 64 + hi * 16);
                acc[mt][0] = __builtin_amdgcn_mfma_f32_16x16x32_bf16(
                    bw1f[kb][0], bf, acc[mt][0], 0, 0, 0);
                acc[mt][1] = __builtin_amdgcn_mfma_f32_16x16x32_bf16(
                    bw1f[kb][1], bf, acc[mt][1], 0, 0, 0);
            }
        // relu + bias -> hsE[edge][hidden]
        #pragma unroll
        for (int mt = 0; mt < 4; ++mt)
            #pragma unroll
            for (int nt = 0; nt < 2; ++nt) {
                bf16x4 hv;
                #pragma unroll
                for (int r = 0; r < 4; ++r)
                    hv[r] = (__bf16)fmaxf(acc[mt][nt][r] + ((const float*)&b1v[nt])[r], 0.f);
                *(bf16x4*)((char*)&sm.hsE[0][0]
                           + (mt * 16 + l15) * 528 + (wcol + nt * 16 + hi * 4) * 2) = hv;
            }
        __syncthreads();   // bar2: hsE ready

        // ---- layer 2: waves 0-3 only, M-split, full K, direct store ----
        if (w < 4) {
            f32x4 a2a = {0.f, 0.f, 0.f, 0.f};
            f32x4 a2b = {0.f, 0.f, 0.f, 0.f};
            #pragma unroll
            for (int kk = 0; kk < 8; kk += 2) {
                const bf16x8 af0 = *(const bf16x8*)((const char*)&sm.hsE[0][0]
                                    + (w * 16 + l15) * 528 + kk * 64 + hi * 16);
                const bf16x8 bf0 = *(const bf16x8*)((const char*)&sm.w2t[0][0]
                                    + l15 * 528 + kk * 64 + hi * 16);
                a2a = __builtin_amdgcn_mfma_f32_16x16x32_bf16(af0, bf0, a2a, 0, 0, 0);
                const bf16x8 af1 = *(const bf16x8*)((const char*)&sm.hsE[0][0]
                                    + (w * 16 + l15) * 528 + (kk + 1) * 64 + hi * 16);
                const bf16x8 bf1 = *(const bf16x8*)((const char*)&sm.w2t[0][0]
                                    + l15 * 528 + (kk + 1) * 64 + hi * 16);
                a2b = __builtin_amdgcn_mfma_f32_16x16x32_bf16(af1, bf1, a2b, 0, 0, 0);
            }
            if (l15 < NBOND) {
                #pragma unroll
                for (int r = 0; r < 4; ++r)
                    outC[(size_t)(e0 + w * 16 + hi * 4 + r) * NBOND + l15]
                        = a2a[r] + a2b[r] + bb2v;
            }
        }
    }
}

// ---------------------------------------------------------------------------
extern "C" void kernel_launch(void* const* d_in, const int* in_sizes, int n_in,
                              void* d_out, int out_size, void* d_ws, size_t ws_size,
                              hipStream_t stream)
{
    const float* pos = (const float*)d_in[0];
    const float* q   = (const float*)d_in[1];
    const int*   pair= (const int*)  d_in[2];
    const float* aW1 = (const float*)d_in[3];
    const float* ab1 = (const float*)d_in[4];
    const float* aW2 = (const float*)d_in[5];
    const float* ab2 = (const float*)d_in[6];
    const float* bW1 = (const float*)d_in[7];
    const float* bb1 = (const float*)d_in[8];
    const float* bW2 = (const float*)d_in[9];
    const float* bb2 = (const float*)d_in[10];

    float* out  = (float*)d_out;
    float* outA = out;
    float* outB = out + (size_t)N_NODES * NTYPES;
    float* outC = out + (size_t)N_NODES * (NTYPES + NCHG);

    const size_t qb_bytes = (size_t)N_NODES * LATENT * sizeof(__bf16);
    const bool use_bf = (ws_size >= qb_bytes);
    __bf16* qb = (__bf16*)d_ws;

    if (use_bf)
        hipLaunchKernelGGL(prep_kernel, dim3(N_NODES * LATENT / (256 * 8)), dim3(256),
                           0, stream, q, qb);

    hipLaunchKernelGGL(atom_kernel, dim3(ANBLK), dim3(256), 0, stream,
                       q, aW1, ab1, aW2, ab2, outA, outB);

    if (use_bf)
        hipLaunchKernelGGL(edge_kernel<true>, dim3(ENBLK), dim3(512), 0, stream,
                           pos, q, qb, pair, bW1, bb1, bW2, bb2, outC);
    else
        hipLaunchKernelGGL(edge_kernel<false>, dim3(ENBLK), dim3(512), 0, stream,
                           pos, q, qb, pair, bW1, bb1, bW2, bb2, outC);
}